// Round 12
// baseline (41.049 us; speedup 1.0000x reference)
//
#include <hip/hip_runtime.h>
#include <stdint.h>

#define NUM_CLASSES 20
#define CPB     49                      // cells per batch
#define KPB     98                      // candidates per batch
#define NCELL   3136
#define NCAND   6272
#define NCHUNK  98                      // 64-candidate chunks
#define NW      8                       // waves per block
#define TPB     512
#define TCELL   256                     // cells per staged tile
#define NROUND  13                      // 12 full tiles + 1 tile of 64 cells

// monotone float -> sortable u32 (ascending float == ascending u32)
__device__ __forceinline__ unsigned fkey(float f) {
    unsigned u = __float_as_uint(f);
    return (u & 0x80000000u) ? ~u : (u | 0x80000000u);
}

// score of one bbox slice q[0..25): conf * max cls prob, mul-then-max chain
__device__ __forceinline__ float cand_score(const float* q) {
    float conf = q[4];
    float m = __fmul_rn(q[5], conf);
    #pragma unroll
    for (int k = 1; k < NUM_CLASSES; ++k)
        m = fmaxf(m, __fmul_rn(q[5 + k], conf));
    return m;
}

__device__ __forceinline__ float iou_rn(float4 a, float4 b) {
    float xx1 = fmaxf(a.x, b.x), yy1 = fmaxf(a.y, b.y);
    float xx2 = fminf(a.z, b.z), yy2 = fminf(a.w, b.w);
    float w = fmaxf(__fsub_rn(xx2, xx1), 0.0f);
    float h = fmaxf(__fsub_rn(yy2, yy1), 0.0f);
    float inter = __fmul_rn(w, h);
    float aa = __fmul_rn(__fsub_rn(a.z, a.x), __fsub_rn(a.w, a.y));
    float ab = __fmul_rn(__fsub_rn(b.z, b.x), __fsub_rn(b.w, b.y));
    float denom = __fadd_rn(__fsub_rn(__fadd_rn(aa, ab), inter), 1e-9f);
    return __fdiv_rn(inter, denom);
}

// ONE dispatch, 98 blocks x 512. Block ib owns output cands [ib*64, ib*64+64).
// Keys for all 6272 cands recomputed per block from LDS-staged coalesced tiles.
__global__ void __launch_bounds__(TPB) k_all(const float* __restrict__ in,
                                             float* __restrict__ out) {
    __shared__ union SMem {
        float4 raw4[TCELL * 50 / 4];              // 51200 B, dead after rounds
        struct {
            unsigned vkey32[NCAND];               // compacted valid keys, idx order
            unsigned long long mkey[NW][KPB];
            unsigned long long skey[NW][KPB];
        } s;
    } u;
    __shared__ float4   lbox[2][CPB];
    __shared__ int      llab[2][CPB];
    __shared__ float    lscore[2][KPB];
    __shared__ unsigned lkeyLo[2][KPB];
    __shared__ float    lkeep[2][KPB];
    __shared__ unsigned chunkCnt[NCHUNK];
    __shared__ unsigned chunkOff[NCHUNK];
    __shared__ unsigned prefVOwn[64];
    __shared__ unsigned rankPart[NW][64];
    __shared__ unsigned nV_s;

    const int tid  = (int)threadIdx.x;
    const int lane = tid & 63;
    const int w    = tid >> 6;
    const int ib   = (int)blockIdx.x;             // 0..97
    const int i0   = ib * 64;
    const int b0   = i0 / KPB;
    const bool need2 = ((i0 + 63) / KPB) > b0;

    if (tid < 2 * KPB) ((float*)lkeep)[tid] = 0.0f;

    // ---- 13 rounds: stage tile r coalesced, compute kreg[r], decode own cells ----
    unsigned kreg[NROUND];
    const float* praw = (const float*)u.raw4;
    for (int r = 0; r < NROUND; ++r) {
        int tileCells = (r < 12) ? TCELL : (NCELL - 12 * TCELL);   // 256 or 64
        int n4 = tileCells * 50 / 4;
        const float4* src4 = (const float4*)in + r * (TCELL * 50 / 4);
        __syncthreads();                           // prior round's raw readers done
        for (int t = tid; t < n4; t += TPB) u.raw4[t] = src4[t];
        __syncthreads();                           // staging visible

        // key for cand (8r+w)*64+lane == tile-local cand tid
        if (tid < tileCells * 2) {
            const float* q = praw + (tid >> 1) * 50 + (tid & 1) * 25;
            float s = cand_score(q);
            kreg[r] = fkey((s > 0.5f) ? -s : __builtin_inff());
        } else {
            kreg[r] = 0xFFFFFFFFu;
        }

        // own-batch decode when its cells are in this tile
        if (tid < 2 * CPB) {
            int bbD = tid / CPB, cl = tid - bbD * CPB;
            int gc = (b0 + bbD) * CPB + cl;
            if ((bbD == 0 || need2) && gc >= r * TCELL && gc < r * TCELL + tileCells) {
                const float* p = praw + (gc - r * TCELL) * 50;
                float s0 = cand_score(p);
                float s1 = cand_score(p + 25);
                int best = (s1 > s0) ? 1 : 0;      // first-occurrence argmax
                const float* q = p + best * 25;
                int lab = 0; float bv = q[5];
                #pragma unroll
                for (int k = 1; k < NUM_CLASSES; ++k)
                    if (q[5 + k] > bv) { bv = q[5 + k]; lab = k; }
                int rr = cl / 7, cc = cl - rr * 7;
                float x  = __fdiv_rn(__fadd_rn(q[0], (float)rr), 7.0f);
                float y  = __fdiv_rn(__fadd_rn(q[1], (float)cc), 7.0f);
                float hw = __fmul_rn(q[2], 0.5f);
                float hh = __fmul_rn(q[3], 0.5f);
                lbox[bbD][cl] = make_float4(__fsub_rn(x, hw), __fsub_rn(y, hh),
                                            __fadd_rn(x, hw), __fadd_rn(y, hh));
                llab[bbD][cl] = lab + 1;
                lscore[bbD][cl * 2]     = s0;
                lscore[bbD][cl * 2 + 1] = s1;
                lkeyLo[bbD][cl * 2]     = fkey((s0 > 0.5f) ? -s0 : __builtin_inff());
                lkeyLo[bbD][cl * 2 + 1] = fkey((s1 > 0.5f) ? -s1 : __builtin_inff());
            }
        }
    }
    __syncthreads();                               // B0: raw dead, union reusable

    // ---- per-chunk valid counts (ballot); kreg[k] holds chunk w+8k ----
    #pragma unroll
    for (int k = 0; k < NROUND; ++k) {
        int ch = NW * k + w;
        if (ch < NCHUNK) {
            unsigned long long bal = __ballot(kreg[k] < 0x80000000u);
            if (lane == 0) chunkCnt[ch] = (unsigned)__popcll(bal);
        }
    }
    __syncthreads();                               // B1
    if (tid < NCHUNK) {
        unsigned off = 0;
        for (int t = 0; t < tid; ++t) off += chunkCnt[t];
        chunkOff[tid] = off;
        if (tid == NCHUNK - 1) nV_s = off + chunkCnt[NCHUNK - 1];
    }
    __syncthreads();                               // B2
    // ---- compacted write (index order) + own prefix-valid ----
    #pragma unroll
    for (int k = 0; k < NROUND; ++k) {
        int ch = NW * k + w;
        if (ch < NCHUNK) {
            bool val = kreg[k] < 0x80000000u;
            unsigned long long bal = __ballot(val);
            unsigned pos = chunkOff[ch] +
                (unsigned)__popcll(bal & ((1ull << lane) - 1ull));
            if (val) u.s.vkey32[pos] = kreg[k];
            if (ch == ib) prefVOwn[lane] = pos;    // #valid with idx < own i
        }
    }

    // ---- NMS: 40 (batch,label) tasks, 5 serial per wave; R10/R11-proven body ----
    for (int it = 0; it < 5; ++it) {
        int task = it * NW + w;                    // 0..39
        int bb = task / NUM_CLASSES;
        int L  = task - bb * NUM_CLASSES + 1;
        bool alive = (bb == 0) || need2;
        int base = (b0 + bb) * KPB;
        bool v0 = false, v1 = false;
        unsigned long long key0 = 0, key1 = 0;
        if (alive) {
            unsigned kl0 = lkeyLo[bb][lane];
            v0 = (kl0 < 0x80000000u) && (llab[bb][lane >> 1] == L);
            key0 = ((unsigned long long)kl0 << 32) | (unsigned)(base + lane);
            if (lane + 64 < KPB) {
                unsigned kl1 = lkeyLo[bb][lane + 64];
                v1 = (kl1 < 0x80000000u) && (llab[bb][(lane + 64) >> 1] == L);
                key1 = ((unsigned long long)kl1 << 32) | (unsigned)(base + lane + 64);
            }
        }
        unsigned long long bal0 = __ballot(v0), bal1 = __ballot(v1);
        int n0 = (int)__popcll(bal0);
        int n  = n0 + (int)__popcll(bal1);
        unsigned long long below = (1ull << lane) - 1ull;
        if (v0) u.s.mkey[w][__popcll(bal0 & below)] = key0;
        if (v1) u.s.mkey[w][n0 + __popcll(bal1 & below)] = key1;
        __syncthreads();                           // mkey visible (uniform)
        if (n > 0) {
            for (int s = 0; s < 2; ++s) {
                int j = lane + s * 64;
                if (j < n) {
                    unsigned long long kj = u.s.mkey[w][j];
                    int rr = 0;
                    for (int i2 = 0; i2 < n; ++i2) rr += (u.s.mkey[w][i2] < kj) ? 1 : 0;
                    u.s.skey[w][rr] = kj;          // rank-by-count == stable sort
                }
            }
        }
        __syncthreads();                           // skey visible (uniform)
        if (n > 0) {
            float4 box0 = make_float4(0.f, 0.f, 0.f, 0.f), box1 = box0;
            int t0 = 0, t1 = 0, keep0 = 0, keep1 = 0;
            if (lane < n) {
                t0 = (int)(unsigned)u.s.skey[w][lane] - base;
                box0 = lbox[bb][t0 >> 1]; keep0 = 1;
            }
            if (lane + 64 < n) {
                t1 = (int)(unsigned)u.s.skey[w][lane + 64] - base;
                box1 = lbox[bb][t1 >> 1]; keep1 = 1;
            }
            for (int g = 0; g < n; ++g) {
                int srcl = g & 63;
                int kg = __shfl((g < 64) ? keep0 : keep1, srcl);
                if (kg) {
                    float4 s4 = (g < 64) ? box0 : box1;
                    float4 bi;
                    bi.x = __shfl(s4.x, srcl); bi.y = __shfl(s4.y, srcl);
                    bi.z = __shfl(s4.z, srcl); bi.w = __shfl(s4.w, srcl);
                    if (keep0 && lane > g)      { if (iou_rn(bi, box0) > 0.3f) keep0 = 0; }
                    if (keep1 && lane + 64 > g) { if (iou_rn(bi, box1) > 0.3f) keep1 = 0; }
                }
            }
            if (keep0) lkeep[bb][t0] = 1.0f;
            if (keep1) lkeep[bb][t1] = 1.0f;
        }
    }
    __syncthreads();                               // B3: vkey32/prefVOwn/lkeep final

    // ---- rank own 64 candidates vs compacted valid keys ----
    const int iG = i0 + lane;
    int bg  = iG / KPB;
    int il  = iG - bg * KPB;
    int bb2 = bg - b0;                             // 0 or 1
    unsigned kiLo = lkeyLo[bb2][il];
    unsigned ci   = prefVOwn[lane];                // compacted pos / #valid<i
    {
        unsigned nV = nV_s;
        int cs = ((int)nV + NW - 1) / NW;
        int j0 = w * cs;
        int j1 = min((int)nV, j0 + cs);
        unsigned acc = 0;
        #pragma unroll 8
        for (int j = j0; j < j1; ++j) {
            unsigned kj = u.s.vkey32[j];           // wave-uniform broadcast read
            acc += (kj < kiLo) ? 1u : 0u;
            acc += (kj == kiLo && (unsigned)j < ci) ? 1u : 0u;  // stable tie-break
        }
        rankPart[w][lane] = acc;
    }
    __syncthreads();                               // B4
    if (tid < 64) {
        unsigned r;
        if (kiLo < 0x80000000u) {                  // valid: sum partials
            r = 0;
            #pragma unroll
            for (int w2 = 0; w2 < NW; ++w2) r += rankPart[w2][lane];
        } else {                                   // invalid: closed form
            r = nV_s + (unsigned)iG - ci;
        }
        out[r] = (float)bg;                        // batch id
        float4 bx = lbox[bb2][il >> 1];
        *(float4*)(out + NCAND + r * 4) = bx;
        out[NCAND * 5 + r] = (float)llab[bb2][il >> 1];
        out[NCAND * 6 + r] = lscore[bb2][il];
        out[NCAND * 7 + r] = lkeep[bb2][il];
    }
}

extern "C" void kernel_launch(void* const* d_in, const int* in_sizes, int n_in,
                              void* d_out, int out_size, void* d_ws, size_t ws_size,
                              hipStream_t stream) {
    const float* in = (const float*)d_in[0];
    float* out = (float*)d_out;
    k_all<<<NCHUNK, TPB, 0, stream>>>(in, out);
}

// Round 13
// 27.333 us; speedup vs baseline: 1.5018x; 1.5018x over previous
//
#include <hip/hip_runtime.h>
#include <stdint.h>

#define NUM_CLASSES 20
#define NUM_GRID    7
#define BATCH   64
#define NCELL   3136
#define NCAND   6272
#define NGROUP  1280
#define CPB     49
#define KPB     98
#define NDECB   49                      // decode blocks
#define NBLK_K1 (NDECB + NGROUP)        // 1329
#define NW      8
#define TPB2    512
#define NCHUNK  98

// ---- workspace layout (bytes) ----
#define WS_SCORE     0         // f32[6272]            25088
#define WS_CELLBOX   25088     // f32[3136*4]          50176
#define WS_CELLLAB   75264     // f32[3136]            12544
#define WS_KEYLO     87808     // u32[6272]            25088
#define WS_KEEP      112896    // f32[6272]            25088

// monotone float -> sortable u32 (ascending float == ascending u32)
__device__ __forceinline__ unsigned fkey(float f) {
    unsigned u = __float_as_uint(f);
    return (u & 0x80000000u) ? ~u : (u | 0x80000000u);
}

__device__ __forceinline__ float cand_score(const float* q) {
    float conf = q[4];
    float m = __fmul_rn(q[5], conf);
    #pragma unroll
    for (int k = 1; k < NUM_CLASSES; ++k)
        m = fmaxf(m, __fmul_rn(q[5 + k], conf));
    return m;
}

__device__ __forceinline__ float iou_rn(float4 a, float4 b) {
    float xx1 = fmaxf(a.x, b.x), yy1 = fmaxf(a.y, b.y);
    float xx2 = fminf(a.z, b.z), yy2 = fminf(a.w, b.w);
    float w = fmaxf(__fsub_rn(xx2, xx1), 0.0f);
    float h = fmaxf(__fsub_rn(yy2, yy1), 0.0f);
    float inter = __fmul_rn(w, h);
    float aa = __fmul_rn(__fsub_rn(a.z, a.x), __fsub_rn(a.w, a.y));
    float ab = __fmul_rn(__fsub_rn(b.z, b.x), __fsub_rn(b.w, b.y));
    float denom = __fadd_rn(__fsub_rn(__fadd_rn(aa, ab), inter), 1e-9f);
    return __fdiv_rn(inter, denom);
}

// Dispatch 1: decode blocks [0,49) + NMS blocks [49,1329). No rank here.
// keepOrig has exactly one writer per candidate (its (batch,label) owner).
__global__ void __launch_bounds__(64) k_decode_nms(
        const float* __restrict__ in,
        float* __restrict__ score,
        float* __restrict__ cellBox,
        float* __restrict__ cellLabel,
        unsigned* __restrict__ keyLo,
        float* __restrict__ keepOrig) {
    __shared__ struct {
        float2 raw2[1225];
        unsigned long long lkey[KPB];
        float4 lbox[CPB];
        int    llab[CPB];
        float  lkeep[KPB];
        unsigned long long mkey[KPB];
        unsigned long long skey[KPB];
    } sm;

    const int bid  = (int)blockIdx.x;
    const int lane = (int)threadIdx.x;

    // ---------------- decode blocks ----------------
    if (bid < NDECB) {
        int cell = bid * 64 + lane;                // covers 3136 exactly
        const float* p = in + cell * 50;
        float s0 = cand_score(p);
        float s1 = cand_score(p + 25);
        int best = (s1 > s0) ? 1 : 0;              // first-occurrence argmax
        const float* q = p + best * 25;

        int lab = 0; float bv = q[5];
        #pragma unroll
        for (int k = 1; k < NUM_CLASSES; ++k)
            if (q[5 + k] > bv) { bv = q[5 + k]; lab = k; }

        int rc = cell % (NUM_GRID * NUM_GRID);
        int r = rc / NUM_GRID, c = rc % NUM_GRID;
        float x  = __fdiv_rn(__fadd_rn(q[0], (float)r), 7.0f);
        float y  = __fdiv_rn(__fadd_rn(q[1], (float)c), 7.0f);
        float hw = __fmul_rn(q[2], 0.5f);
        float hh = __fmul_rn(q[3], 0.5f);
        *(float4*)(cellBox + cell * 4) =
            make_float4(__fsub_rn(x, hw), __fsub_rn(y, hh),
                        __fadd_rn(x, hw), __fadd_rn(y, hh));
        cellLabel[cell] = (float)(lab + 1);
        score[cell * 2 + 0] = s0;
        score[cell * 2 + 1] = s1;
        keyLo[cell * 2 + 0] = fkey((s0 > 0.5f) ? -s0 : __builtin_inff());
        keyLo[cell * 2 + 1] = fkey((s1 > 0.5f) ? -s1 : __builtin_inff());
        return;
    }

    // ---------------- NMS blocks (R10-proven body) ----------------
    int g = bid - NDECB;
    int b = g / NUM_CLASSES;
    int L = g % NUM_CLASSES + 1;
    int base = b * KPB;

    const float2* src = (const float2*)(in + b * (CPB * 50));
    for (int t = lane; t < 1225; t += 64) sm.raw2[t] = src[t];
    sm.lkeep[lane] = 0.0f;
    if (lane + 64 < KPB) sm.lkeep[lane + 64] = 0.0f;
    __syncthreads();

    if (lane < CPB) {
        const float* p = (const float*)sm.raw2 + lane * 50;
        float s0 = cand_score(p);
        float s1 = cand_score(p + 25);
        int best = (s1 > s0) ? 1 : 0;
        const float* q = p + best * 25;

        int lab = 0; float bv = q[5];
        #pragma unroll
        for (int k = 1; k < NUM_CLASSES; ++k)
            if (q[5 + k] > bv) { bv = q[5 + k]; lab = k; }

        int r = lane / NUM_GRID, c = lane % NUM_GRID;
        float x  = __fdiv_rn(__fadd_rn(q[0], (float)r), 7.0f);
        float y  = __fdiv_rn(__fadd_rn(q[1], (float)c), 7.0f);
        float hw = __fmul_rn(q[2], 0.5f);
        float hh = __fmul_rn(q[3], 0.5f);
        sm.lbox[lane] = make_float4(__fsub_rn(x, hw), __fsub_rn(y, hh),
                                    __fadd_rn(x, hw), __fadd_rn(y, hh));
        sm.llab[lane] = lab + 1;
        {
            bool v = s0 > 0.5f;
            float kf = v ? -s0 : __builtin_inff();
            sm.lkey[lane * 2] =
                ((unsigned long long)fkey(kf) << 32) | (unsigned)(base + lane * 2);
        }
        {
            bool v = s1 > 0.5f;
            float kf = v ? -s1 : __builtin_inff();
            sm.lkey[lane * 2 + 1] =
                ((unsigned long long)fkey(kf) << 32) | (unsigned)(base + lane * 2 + 1);
        }
    }
    __syncthreads();

    unsigned long long key0 = sm.lkey[lane];
    int lab0 = sm.llab[lane >> 1];
    bool v0 = ((unsigned)(key0 >> 32) < 0x80000000u) && (lab0 == L);
    unsigned long long key1 = 0; bool v1 = false; int lab1 = -1;
    if (lane + 64 < KPB) {
        key1 = sm.lkey[lane + 64];
        lab1 = sm.llab[(lane + 64) >> 1];
        v1 = ((unsigned)(key1 >> 32) < 0x80000000u) && (lab1 == L);
    }
    unsigned long long b0 = __ballot(v0);
    unsigned long long b1 = __ballot(v1);
    int n0 = __popcll(b0);
    int n  = n0 + __popcll(b1);
    unsigned long long below = (1ull << lane) - 1ull;
    if (v0) sm.mkey[__popcll(b0 & below)] = key0;
    if (v1) sm.mkey[n0 + __popcll(b1 & below)] = key1;
    __syncthreads();

    if (n > 0) {
        for (int s = 0; s < 2; ++s) {
            int j = lane + s * 64;
            if (j < n) {
                unsigned long long kj = sm.mkey[j];
                int rr = 0;
                for (int i2 = 0; i2 < n; ++i2) rr += (sm.mkey[i2] < kj) ? 1 : 0;
                sm.skey[rr] = kj;                  // rank-by-count == stable sort
            }
        }
    }
    __syncthreads();

    if (n > 0) {
        float4 box0 = make_float4(0.f, 0.f, 0.f, 0.f), box1 = box0;
        int t0 = 0, t1 = 0, keep0 = 0, keep1 = 0;
        if (lane < n) {
            t0 = (int)(unsigned)sm.skey[lane] - base;
            box0 = sm.lbox[t0 >> 1]; keep0 = 1;
        }
        if (lane + 64 < n) {
            t1 = (int)(unsigned)sm.skey[lane + 64] - base;
            box1 = sm.lbox[t1 >> 1]; keep1 = 1;
        }
        for (int i = 0; i < n; ++i) {
            int srcl = i & 63;
            int ki = __shfl((i < 64) ? keep0 : keep1, srcl);
            if (ki) {
                float4 s4 = (i < 64) ? box0 : box1;
                float4 bi;
                bi.x = __shfl(s4.x, srcl); bi.y = __shfl(s4.y, srcl);
                bi.z = __shfl(s4.z, srcl); bi.w = __shfl(s4.w, srcl);
                if (keep0 && lane > i)      { if (iou_rn(bi, box0) > 0.3f) keep0 = 0; }
                if (keep1 && lane + 64 > i) { if (iou_rn(bi, box1) > 0.3f) keep1 = 0; }
            }
        }
        if (keep0) sm.lkeep[t0] = 1.0f;
        if (keep1) sm.lkeep[t1] = 1.0f;
    }
    __syncthreads();

    // keep for exactly this block's label (disjoint-complete across blocks)
    if (lab0 == L) keepOrig[base + lane] = sm.lkeep[lane];
    if (lane + 64 < KPB && lab1 == L) keepOrig[base + lane + 64] = sm.lkeep[lane + 64];
}

// Dispatch 2: 98 blocks x 512. Compact valid keys (R11-proven machinery),
// rank own 64 candidates (valid: ~370-iter compare; invalid: closed form),
// scatter all outputs.
__global__ void __launch_bounds__(TPB2) k_rank_scatter(
        const unsigned* __restrict__ keyLo,
        const float* __restrict__ score,
        const float* __restrict__ cellBox,
        const float* __restrict__ cellLabel,
        const float* __restrict__ keepOrig,
        float* __restrict__ out) {
    __shared__ unsigned vkey[NCAND];               // compacted valid keys, idx order
    __shared__ unsigned chunkCnt[NCHUNK];
    __shared__ unsigned chunkOff[NCHUNK];
    __shared__ unsigned prefVOwn[64];
    __shared__ unsigned rankPart[NW][64];
    __shared__ unsigned nV_s;

    const int tid  = (int)threadIdx.x;
    const int lane = tid & 63;
    const int w    = tid >> 6;
    const int ib   = (int)blockIdx.x;              // 0..97
    const int i0   = ib * 64;

    // coalesced key loads: wave w holds chunks w+8k
    unsigned kreg[13];
    #pragma unroll
    for (int k = 0; k < 13; ++k) {
        int ch = NW * k + w;
        kreg[k] = (ch < NCHUNK) ? keyLo[ch * 64 + lane] : 0xFFFFFFFFu;
    }
    #pragma unroll
    for (int k = 0; k < 13; ++k) {
        int ch = NW * k + w;
        if (ch < NCHUNK) {
            unsigned long long bal = __ballot(kreg[k] < 0x80000000u);
            if (lane == 0) chunkCnt[ch] = (unsigned)__popcll(bal);
        }
    }
    __syncthreads();                               // B1
    if (tid < NCHUNK) {
        unsigned off = 0;
        for (int t = 0; t < tid; ++t) off += chunkCnt[t];
        chunkOff[tid] = off;
        if (tid == NCHUNK - 1) nV_s = off + chunkCnt[NCHUNK - 1];
    }
    __syncthreads();                               // B2
    #pragma unroll
    for (int k = 0; k < 13; ++k) {
        int ch = NW * k + w;
        if (ch < NCHUNK) {
            bool val = kreg[k] < 0x80000000u;
            unsigned long long bal = __ballot(val);
            unsigned pos = chunkOff[ch] +
                (unsigned)__popcll(bal & ((1ull << lane) - 1ull));
            if (val) vkey[pos] = kreg[k];
            if (ch == ib) prefVOwn[lane] = pos;    // #valid with idx < own i
        }
    }
    __syncthreads();                               // B3: vkey/prefVOwn visible

    // rank own 64 candidates vs compacted valid keys
    const int iG = i0 + lane;
    unsigned kiLo = keyLo[iG];                     // coalesced, L2-hot
    unsigned ci   = prefVOwn[lane];
    {
        unsigned nV = nV_s;
        int cs = ((int)nV + NW - 1) / NW;
        int j0 = w * cs;
        int j1 = min((int)nV, j0 + cs);
        unsigned acc = 0;
        #pragma unroll 8
        for (int j = j0; j < j1; ++j) {
            unsigned kj = vkey[j];                 // wave-uniform broadcast read
            acc += (kj < kiLo) ? 1u : 0u;
            acc += (kj == kiLo && (unsigned)j < ci) ? 1u : 0u;  // stable tie-break
        }
        rankPart[w][lane] = acc;
    }
    __syncthreads();                               // B4
    if (tid < 64) {
        unsigned r;
        if (kiLo < 0x80000000u) {
            r = 0;
            #pragma unroll
            for (int w2 = 0; w2 < NW; ++w2) r += rankPart[w2][lane];
        } else {
            r = nV_s + (unsigned)iG - ci;          // closed form for invalid
        }
        int cell = iG >> 1;
        out[r] = (float)(iG / KPB);                // batch id
        float4 bx = *(const float4*)(cellBox + cell * 4);
        *(float4*)(out + NCAND + r * 4) = bx;
        out[NCAND * 5 + r] = cellLabel[cell];
        out[NCAND * 6 + r] = score[iG];
        out[NCAND * 7 + r] = keepOrig[iG];
    }
}

extern "C" void kernel_launch(void* const* d_in, const int* in_sizes, int n_in,
                              void* d_out, int out_size, void* d_ws, size_t ws_size,
                              hipStream_t stream) {
    const float* in = (const float*)d_in[0];
    char* ws = (char*)d_ws;
    float*    score     = (float*)(ws + WS_SCORE);
    float*    cellBox   = (float*)(ws + WS_CELLBOX);
    float*    cellLabel = (float*)(ws + WS_CELLLAB);
    unsigned* keyLo     = (unsigned*)(ws + WS_KEYLO);
    float*    keepOrig  = (float*)(ws + WS_KEEP);
    float* out = (float*)d_out;

    k_decode_nms<<<NBLK_K1, 64, 0, stream>>>(in, score, cellBox, cellLabel,
                                             keyLo, keepOrig);
    k_rank_scatter<<<NCHUNK, TPB2, 0, stream>>>(keyLo, score, cellBox, cellLabel,
                                                keepOrig, out);
}